// Round 4
// baseline (330.169 us; speedup 1.0000x reference)
//
#include <hip/hip_runtime.h>
#include <hip/hip_bf16.h>

// y[b,i] = sum_j x[b,j] * r[(j-i) mod N] + bias[i]
// xb = bf16(x), Bt[i][k] = bf16(r[(k-i)&mask]) in ws.
// GEMM: 256x256 tile, BK=32, ring-4 K-slot pipeline with counted vmcnt(4).

typedef __attribute__((ext_vector_type(8))) short bf16x8;
typedef __attribute__((ext_vector_type(4))) float f32x4;
typedef __attribute__((ext_vector_type(8))) unsigned short us8;
typedef __attribute__((ext_vector_type(4))) unsigned short us4;

__device__ __forceinline__ unsigned short f2bf(float f) {
  union { __hip_bfloat16 h; unsigned short u; } v;
  v.h = __float2bfloat16(f);
  return v.u;
}

__device__ __forceinline__ void gload_lds16(const void* g, void* l) {
  __builtin_amdgcn_global_load_lds(
      (const __attribute__((address_space(1))) void*)g,
      (__attribute__((address_space(3))) void*)l, 16, 0, 0);
}

#define SBAR() __builtin_amdgcn_s_barrier()
#define SCHED0() __builtin_amdgcn_sched_barrier(0)
#define LGKM0() asm volatile("s_waitcnt lgkmcnt(0)" ::: "memory")
#define VM0() asm volatile("s_waitcnt vmcnt(0)" ::: "memory")
#define VM4() asm volatile("s_waitcnt vmcnt(4)" ::: "memory")

// ---------------- converters ----------------

__global__ __launch_bounds__(256) void conv_x_kernel(
    const float* __restrict__ x, unsigned short* __restrict__ xb,
    size_t total8) {
  size_t i = (size_t)blockIdx.x * blockDim.x + threadIdx.x;
  const size_t stride = (size_t)gridDim.x * blockDim.x;
  for (; i < total8; i += stride) {
    const float4 v0 = ((const float4*)x)[2 * i];
    const float4 v1 = ((const float4*)x)[2 * i + 1];
    us8 o;
    o[0] = f2bf(v0.x); o[1] = f2bf(v0.y); o[2] = f2bf(v0.z); o[3] = f2bf(v0.w);
    o[4] = f2bf(v1.x); o[5] = f2bf(v1.y); o[6] = f2bf(v1.z); o[7] = f2bf(v1.w);
    ((us8*)xb)[i] = o;
  }
}

__global__ __launch_bounds__(256) void build_bt_kernel(
    const float* __restrict__ r, unsigned short* __restrict__ bt, int n,
    int logn) {
  const int mask = n - 1;
  const size_t total8 = ((size_t)n * n) >> 3;
  size_t i = (size_t)blockIdx.x * blockDim.x + threadIdx.x;
  const size_t stride = (size_t)gridDim.x * blockDim.x;
  for (; i < total8; i += stride) {
    const size_t e0 = i << 3;
    const int row = (int)(e0 >> logn);
    const int k0 = (int)(e0 & (size_t)mask);
    const int base = k0 - row;
    us8 o;
#pragma unroll
    for (int t = 0; t < 8; ++t) o[t] = f2bf(r[(base + t) & mask]);
    ((us8*)bt)[i] = o;
  }
}

// ---------------- 256x256 GEMM, BK=32, ring-4, counted vmcnt ----------------
// 8 waves (2M x 4N); per-wave C = 128x64 = acc[8][4] 16x16 frags.
// LDS: 4 K-slots x (A 256x32 + B 256x32) bf16 = 128 KiB.
// Slot layout: [row][4 chunks of 8 elems], phys_chunk = logical ^ ((row>>1)&3).
// Block t: reads slot t&3, stages tile t+2 into slot (t+2)&3 (2-block gap).
// Block-end wait: vmcnt(4) (own 4 stage-loads in flight) -> never drains to 0.

#define ASLOT 8192  // elems per slot (256*32)

__global__ __launch_bounds__(512, 2) void circ_gemm4(
    const unsigned short* __restrict__ A, const unsigned short* __restrict__ B,
    const float* __restrict__ bias, float* __restrict__ y, int n, int nbn) {
  __shared__ unsigned short As[4 * ASLOT];
  __shared__ unsigned short Bs[4 * ASLOT];

  // XCD-aware swizzle (nwg % 8 == 0: 512 blocks)
  const int nwg = gridDim.x;
  const int cpx = nwg >> 3;
  const int b0 = blockIdx.x;
  const int wg = (b0 & 7) * cpx + (b0 >> 3);
  const int bn0 = (wg % nbn) * 256;
  const int bm0 = (wg / nbn) * 256;

  const int tid = threadIdx.x;
  const int wid = tid >> 6;
  const int lane = tid & 63;
  const int wm = wid >> 2;  // 0..1
  const int wn = wid & 3;   // 0..3
  const int lr = lane & 15;
  const int g = lane >> 4;  // 0..3 (logical k-chunk)

  // ---- staging addressing ----
  // inst j (j=0,1) of wave w writes slot rows (w*2+j)*16 .. +15, linearly:
  // lane l -> row instrow+(l>>2), phys chunk l&3.
  // source logical chunk = (l&3) ^ ((l>>3)&3)   [derived: (row>>1)&3 == (l>>3)&3]
  const int lchunk = (lane & 3) ^ ((lane >> 3) & 3);
  unsigned aoff[2], boff[2];
  int ldso[2];
#pragma unroll
  for (int j = 0; j < 2; ++j) {
    const int instrow = (wid * 2 + j) * 16;
    aoff[j] = (unsigned)(bm0 + instrow + (lane >> 2)) * (unsigned)n + lchunk * 8;
    boff[j] = (unsigned)(bn0 + instrow + (lane >> 2)) * (unsigned)n + lchunk * 8;
    ldso[j] = instrow * 32;  // elems within slot
  }

  f32x4 acc[8][4];
#pragma unroll
  for (int i = 0; i < 8; ++i)
#pragma unroll
    for (int j = 0; j < 4; ++j) acc[i][j] = (f32x4){0.f, 0.f, 0.f, 0.f};

  const int aRow = wm * 128 + lr;               // + mi*16
  const int bRow = wn * 64 + lr;                // + ni*16
  const int csw = (g ^ ((lr >> 1) & 3)) << 3;   // swizzled chunk elem offset

  const int nt = n >> 5;  // K-tiles of 32

  // ---- prologue: stage tiles 0 (slot 0) and 1 (slot 1) ----
#pragma unroll
  for (int j = 0; j < 2; ++j) gload_lds16(A + aoff[j], As + ldso[j]);
#pragma unroll
  for (int j = 0; j < 2; ++j) gload_lds16(B + boff[j], Bs + ldso[j]);
#pragma unroll
  for (int j = 0; j < 2; ++j) gload_lds16(A + aoff[j] + 32, As + ASLOT + ldso[j]);
#pragma unroll
  for (int j = 0; j < 2; ++j) gload_lds16(B + boff[j] + 32, Bs + ASLOT + ldso[j]);
  VM4();  // tile 0 (oldest 4 loads) landed; tile 1 still in flight
  SCHED0();
  SBAR();
  SCHED0();

  for (int t = 0; t < nt; ++t) {
    const int rslot = (t & 3) * ASLOT;
    const int wslot = ((t + 2) & 3) * ASLOT;
    const unsigned short* Ac = As + rslot;
    const unsigned short* Bc = Bs + rslot;
    const unsigned kof = (unsigned)(t + 2) << 5;
    const bool pf = (t + 2) < nt;

    bf16x8 a0[4], a1[4], bf[4];

    // ===== phase A: read A(mi0-3) + B(ni0-3); stage inst0 of tile t+2 =====
#pragma unroll
    for (int mi = 0; mi < 4; ++mi)
      a0[mi] = *(const bf16x8*)&Ac[(aRow + mi * 16) * 32 + csw];
#pragma unroll
    for (int ni = 0; ni < 4; ++ni)
      bf[ni] = *(const bf16x8*)&Bc[(bRow + ni * 16) * 32 + csw];
    if (pf) {
      gload_lds16(A + aoff[0] + kof, As + wslot + ldso[0]);
      gload_lds16(B + boff[0] + kof, Bs + wslot + ldso[0]);
    }
    SCHED0(); SBAR(); LGKM0(); SCHED0();
    __builtin_amdgcn_s_setprio(1);
#pragma unroll
    for (int mi = 0; mi < 4; ++mi)
#pragma unroll
      for (int ni = 0; ni < 4; ++ni)
        acc[mi][ni] = __builtin_amdgcn_mfma_f32_16x16x32_bf16(
            a0[mi], bf[ni], acc[mi][ni], 0, 0, 0);
    __builtin_amdgcn_s_setprio(0);
    SCHED0(); SBAR(); SCHED0();

    // ===== phase B: read A(mi4-7); stage inst1 of tile t+2 =====
#pragma unroll
    for (int mi = 0; mi < 4; ++mi)
      a1[mi] = *(const bf16x8*)&Ac[(aRow + 64 + mi * 16) * 32 + csw];
    if (pf) {
      gload_lds16(A + aoff[1] + kof, As + wslot + ldso[1]);
      gload_lds16(B + boff[1] + kof, Bs + wslot + ldso[1]);
    }
    SCHED0(); SBAR(); LGKM0(); SCHED0();
    __builtin_amdgcn_s_setprio(1);
#pragma unroll
    for (int mi = 0; mi < 4; ++mi)
#pragma unroll
      for (int ni = 0; ni < 4; ++ni)
        acc[4 + mi][ni] = __builtin_amdgcn_mfma_f32_16x16x32_bf16(
            a1[mi], bf[ni], acc[4 + mi][ni], 0, 0, 0);
    __builtin_amdgcn_s_setprio(0);
    // counted wait: own newest 4 stage-loads may stay in flight;
    // everything older (tile t+1) has landed. Tail: drain once.
    if (pf) {
      VM4();
    } else if (t + 1 < nt) {
      VM0();
    }
    SCHED0(); SBAR(); SCHED0();
  }

  // ---- epilogue: C/D layout col=lane&15, row=(lane>>4)*4+reg ----
#pragma unroll
  for (int ni = 0; ni < 4; ++ni) {
    const int col = bn0 + wn * 64 + ni * 16 + lr;
    const float bv = bias[col];
#pragma unroll
    for (int mi = 0; mi < 8; ++mi) {
      const int row0 = bm0 + wm * 128 + mi * 16 + g * 4;
#pragma unroll
      for (int j = 0; j < 4; ++j)
        y[(size_t)(row0 + j) * n + col] = acc[mi][ni][j] + bv;
    }
  }
}

// ---------------- fallback (no ws needed) ----------------

#define LDP 72

__global__ __launch_bounds__(256) void circ_gemm_fb(
    const float* __restrict__ x, const float* __restrict__ r,
    const float* __restrict__ bias, float* __restrict__ y, int n) {
  __shared__ unsigned short Asf[128][LDP];
  __shared__ unsigned short Bsf[128][LDP];

  const int tid = threadIdx.x;
  const int wid = tid >> 6;
  const int lane = tid & 63;
  const int bm0 = blockIdx.y * 128;
  const int bn0 = blockIdx.x * 128;
  const int m0w = (wid >> 1) * 64;
  const int n0w = (wid & 1) * 64;
  const int lr = lane & 15;
  const int lk = (lane >> 4) * 8;
  const int mask = n - 1;

  f32x4 acc[4][4];
#pragma unroll
  for (int i = 0; i < 4; ++i)
#pragma unroll
    for (int j = 0; j < 4; ++j) acc[i][j] = (f32x4){0.f, 0.f, 0.f, 0.f};

  const int arow = tid >> 4;
  const int acol = (tid & 15) * 4;
  const int bnn = tid >> 1;
  const int bk0 = (tid & 1) * 32;

  for (int k0 = 0; k0 < n; k0 += 64) {
#pragma unroll
    for (int p = 0; p < 8; ++p) {
      const float4 v =
          *(const float4*)&x[(size_t)(bm0 + arow + p * 16) * n + k0 + acol];
      us4 hh;
      hh.x = f2bf(v.x); hh.y = f2bf(v.y); hh.z = f2bf(v.z); hh.w = f2bf(v.w);
      *(us4*)&Asf[arow + p * 16][acol] = hh;
    }
    {
      const int base = k0 + bk0 - bn0 - bnn;
#pragma unroll
      for (int kq = 0; kq < 32; kq += 4) {
        us4 hh;
        hh.x = f2bf(r[(base + kq + 0) & mask]);
        hh.y = f2bf(r[(base + kq + 1) & mask]);
        hh.z = f2bf(r[(base + kq + 2) & mask]);
        hh.w = f2bf(r[(base + kq + 3) & mask]);
        *(us4*)&Bsf[bnn][bk0 + kq] = hh;
      }
    }
    __syncthreads();

#pragma unroll
    for (int kk = 0; kk < 2; ++kk) {
      bf16x8 af[4], bfr[4];
#pragma unroll
      for (int mi = 0; mi < 4; ++mi)
        af[mi] = *(const bf16x8*)&Asf[m0w + mi * 16 + lr][kk * 32 + lk];
#pragma unroll
      for (int ni = 0; ni < 4; ++ni)
        bfr[ni] = *(const bf16x8*)&Bsf[n0w + ni * 16 + lr][kk * 32 + lk];
#pragma unroll
      for (int mi = 0; mi < 4; ++mi)
#pragma unroll
        for (int ni = 0; ni < 4; ++ni)
          acc[mi][ni] = __builtin_amdgcn_mfma_f32_16x16x32_bf16(
              af[mi], bfr[ni], acc[mi][ni], 0, 0, 0);
    }
    __syncthreads();
  }

#pragma unroll
  for (int ni = 0; ni < 4; ++ni) {
    const int col = bn0 + n0w + ni * 16 + lr;
    const float bv = bias[col];
#pragma unroll
    for (int mi = 0; mi < 4; ++mi) {
      const int row0 = bm0 + m0w + mi * 16 + (lane >> 4) * 4;
#pragma unroll
      for (int j = 0; j < 4; ++j)
        y[(size_t)(row0 + j) * n + col] = acc[mi][ni][j] + bv;
    }
  }
}

// ---------------- launch ----------------

extern "C" void kernel_launch(void* const* d_in, const int* in_sizes, int n_in,
                              void* d_out, int out_size, void* d_ws,
                              size_t ws_size, hipStream_t stream) {
  const float* x = (const float*)d_in[0];
  const float* r = (const float*)d_in[1];
  const float* b = (const float*)d_in[2];
  float* y = (float*)d_out;
  const int n = in_sizes[1];          // 4096
  const int batch = in_sizes[0] / n;  // 8192

  const size_t xb_elems = (size_t)batch * n;
  const size_t bt_elems = (size_t)n * n;
  const size_t need = (xb_elems + bt_elems) * sizeof(unsigned short);

  if (ws_size >= need && (n % 256) == 0 && (batch % 256) == 0) {
    unsigned short* xb = (unsigned short*)d_ws;
    unsigned short* bt = xb + xb_elems;
    int logn = 31 - __builtin_clz((unsigned)n);
    conv_x_kernel<<<2048, 256, 0, stream>>>(x, xb, xb_elems / 8);
    build_bt_kernel<<<1024, 256, 0, stream>>>(r, bt, n, logn);
    dim3 grid((batch / 256) * (n / 256));
    circ_gemm4<<<grid, 512, 0, stream>>>(xb, bt, b, y, n, n / 256);
  } else {
    dim3 grid(n / 128, batch / 128);
    circ_gemm_fb<<<grid, 256, 0, stream>>>(x, r, b, y, n);
  }
}

// Round 5
// 316.243 us; speedup vs baseline: 1.0440x; 1.0440x over previous
//
#include <hip/hip_runtime.h>
#include <hip/hip_bf16.h>

// y[b,i] = sum_j x[b,j] * r[(j-i) mod N] + bias[i]
// xb = bf16(x), Bt[i][k] = bf16(r[(k-i)&mask]) in ws.
// GEMM: 256x256 tile, BK=32, ring-4 K-slots, counted vmcnt(4),
//       ONE barrier per K-tile, no sched walls (compiler free to pipeline).

typedef __attribute__((ext_vector_type(8))) short bf16x8;
typedef __attribute__((ext_vector_type(4))) float f32x4;
typedef __attribute__((ext_vector_type(8))) unsigned short us8;
typedef __attribute__((ext_vector_type(4))) unsigned short us4;

__device__ __forceinline__ unsigned short f2bf(float f) {
  union { __hip_bfloat16 h; unsigned short u; } v;
  v.h = __float2bfloat16(f);
  return v.u;
}

__device__ __forceinline__ void gload_lds16(const void* g, void* l) {
  __builtin_amdgcn_global_load_lds(
      (const __attribute__((address_space(1))) void*)g,
      (__attribute__((address_space(3))) void*)l, 16, 0, 0);
}

#define SBAR() __builtin_amdgcn_s_barrier()
#define VM0() asm volatile("s_waitcnt vmcnt(0)" ::: "memory")
#define VM4() asm volatile("s_waitcnt vmcnt(4)" ::: "memory")

// ---------------- converters ----------------

__global__ __launch_bounds__(256) void conv_x_kernel(
    const float* __restrict__ x, unsigned short* __restrict__ xb,
    size_t total8) {
  size_t i = (size_t)blockIdx.x * blockDim.x + threadIdx.x;
  const size_t stride = (size_t)gridDim.x * blockDim.x;
  for (; i < total8; i += stride) {
    const float4 v0 = ((const float4*)x)[2 * i];
    const float4 v1 = ((const float4*)x)[2 * i + 1];
    us8 o;
    o[0] = f2bf(v0.x); o[1] = f2bf(v0.y); o[2] = f2bf(v0.z); o[3] = f2bf(v0.w);
    o[4] = f2bf(v1.x); o[5] = f2bf(v1.y); o[6] = f2bf(v1.z); o[7] = f2bf(v1.w);
    ((us8*)xb)[i] = o;
  }
}

__global__ __launch_bounds__(256) void build_bt_kernel(
    const float* __restrict__ r, unsigned short* __restrict__ bt, int n,
    int logn) {
  const int mask = n - 1;
  const size_t total8 = ((size_t)n * n) >> 3;
  size_t i = (size_t)blockIdx.x * blockDim.x + threadIdx.x;
  const size_t stride = (size_t)gridDim.x * blockDim.x;
  for (; i < total8; i += stride) {
    const size_t e0 = i << 3;
    const int row = (int)(e0 >> logn);
    const int k0 = (int)(e0 & (size_t)mask);
    const int base = k0 - row;
    us8 o;
#pragma unroll
    for (int t = 0; t < 8; ++t) o[t] = f2bf(r[(base + t) & mask]);
    ((us8*)bt)[i] = o;
  }
}

// ---------------- 256x256 GEMM, BK=32, ring-4, free-run phases ----------------
// 8 waves (2M x 4N); per-wave C = 128x64 = acc[8][4] 16x16 frags.
// LDS: 4 K-slots x (A 256x32 + B 256x32) bf16 = 128 KiB.
// Slot layout: [row][4 chunks of 8 elems], phys_chunk = logical ^ ((row>>1)&3).
// Tile t: reads slot t&3, stages tile t+2 into slot (t+2)&3 (>=2-tile gap).
// Sync: VM4 + ONE s_barrier per tile. Safety: slot (t+2)&3's previous readers
// were at tile t-2, which finished before the t-1 tile-end barrier; every wave
// passes VM4 (own stage loads for slot t+1 landed) before arriving at the
// barrier, so after release all waves' slot-(t+1) data is visible. Wave drift
// inside a tile is harmless (writers and readers 2 tiles apart).

#define ASLOT 8192  // elems per slot (256*32)

__global__ __launch_bounds__(512, 2) void circ_gemm5(
    const unsigned short* __restrict__ A, const unsigned short* __restrict__ B,
    const float* __restrict__ bias, float* __restrict__ y, int n, int nbn) {
  __shared__ unsigned short As[4 * ASLOT];
  __shared__ unsigned short Bs[4 * ASLOT];

  // XCD-aware swizzle (nwg % 8 == 0: 512 blocks)
  const int nwg = gridDim.x;
  const int cpx = nwg >> 3;
  const int b0 = blockIdx.x;
  const int wg = (b0 & 7) * cpx + (b0 >> 3);
  const int bn0 = (wg % nbn) * 256;
  const int bm0 = (wg / nbn) * 256;

  const int tid = threadIdx.x;
  const int wid = tid >> 6;
  const int lane = tid & 63;
  const int wm = wid >> 2;  // 0..1
  const int wn = wid & 3;   // 0..3
  const int lr = lane & 15;
  const int g = lane >> 4;  // 0..3 (logical k-chunk)

  // ---- staging addressing ----
  // inst j (j=0,1) of wave w writes slot rows (w*2+j)*16 .. +15, linearly:
  // lane l -> row instrow+(l>>2), phys chunk l&3.
  // source logical chunk = (l&3) ^ ((l>>3)&3)
  const int lchunk = (lane & 3) ^ ((lane >> 3) & 3);
  unsigned aoff[2], boff[2];
  int ldso[2];
#pragma unroll
  for (int j = 0; j < 2; ++j) {
    const int instrow = (wid * 2 + j) * 16;
    aoff[j] = (unsigned)(bm0 + instrow + (lane >> 2)) * (unsigned)n + lchunk * 8;
    boff[j] = (unsigned)(bn0 + instrow + (lane >> 2)) * (unsigned)n + lchunk * 8;
    ldso[j] = instrow * 32;  // elems within slot
  }

  f32x4 acc[8][4];
#pragma unroll
  for (int i = 0; i < 8; ++i)
#pragma unroll
    for (int j = 0; j < 4; ++j) acc[i][j] = (f32x4){0.f, 0.f, 0.f, 0.f};

  const int aRow = wm * 128 + lr;               // + mi*16
  const int bRow = wn * 64 + lr;                // + ni*16
  const int csw = (g ^ ((lr >> 1) & 3)) << 3;   // swizzled chunk elem offset

  const int nt = n >> 5;  // K-tiles of 32

  // ---- prologue: stage tiles 0 (slot 0) and 1 (slot 1) ----
#pragma unroll
  for (int j = 0; j < 2; ++j) gload_lds16(A + aoff[j], As + ldso[j]);
#pragma unroll
  for (int j = 0; j < 2; ++j) gload_lds16(B + boff[j], Bs + ldso[j]);
#pragma unroll
  for (int j = 0; j < 2; ++j) gload_lds16(A + aoff[j] + 32, As + ASLOT + ldso[j]);
#pragma unroll
  for (int j = 0; j < 2; ++j) gload_lds16(B + boff[j] + 32, Bs + ASLOT + ldso[j]);
  VM4();  // tile 0 (oldest 4 loads) landed; tile 1 still in flight
  SBAR();

  for (int t = 0; t < nt; ++t) {
    const int rslot = (t & 3) * ASLOT;
    const int wslot = ((t + 2) & 3) * ASLOT;
    const unsigned short* Ac = As + rslot;
    const unsigned short* Bc = Bs + rslot;
    const unsigned kof = (unsigned)(t + 2) << 5;
    const bool pf = (t + 2) < nt;

    bf16x8 a0[4], a1[4], bf[4];

    // ===== phase A: read A(mi0-3) + B(ni0-3); stage inst0 of tile t+2 =====
#pragma unroll
    for (int mi = 0; mi < 4; ++mi)
      a0[mi] = *(const bf16x8*)&Ac[(aRow + mi * 16) * 32 + csw];
#pragma unroll
    for (int ni = 0; ni < 4; ++ni)
      bf[ni] = *(const bf16x8*)&Bc[(bRow + ni * 16) * 32 + csw];
    if (pf) {
      gload_lds16(A + aoff[0] + kof, As + wslot + ldso[0]);
      gload_lds16(B + boff[0] + kof, Bs + wslot + ldso[0]);
    }
    __builtin_amdgcn_s_setprio(1);
#pragma unroll
    for (int mi = 0; mi < 4; ++mi)
#pragma unroll
      for (int ni = 0; ni < 4; ++ni)
        acc[mi][ni] = __builtin_amdgcn_mfma_f32_16x16x32_bf16(
            a0[mi], bf[ni], acc[mi][ni], 0, 0, 0);
    __builtin_amdgcn_s_setprio(0);

    // ===== phase B: read A(mi4-7); stage inst1 of tile t+2 =====
#pragma unroll
    for (int mi = 0; mi < 4; ++mi)
      a1[mi] = *(const bf16x8*)&Ac[(aRow + 64 + mi * 16) * 32 + csw];
    if (pf) {
      gload_lds16(A + aoff[1] + kof, As + wslot + ldso[1]);
      gload_lds16(B + boff[1] + kof, Bs + wslot + ldso[1]);
    }
    __builtin_amdgcn_s_setprio(1);
#pragma unroll
    for (int mi = 0; mi < 4; ++mi)
#pragma unroll
      for (int ni = 0; ni < 4; ++ni)
        acc[4 + mi][ni] = __builtin_amdgcn_mfma_f32_16x16x32_bf16(
            a1[mi], bf[ni], acc[4 + mi][ni], 0, 0, 0);
    __builtin_amdgcn_s_setprio(0);

    // ===== tile boundary: counted wait + single barrier =====
    if (pf) {
      VM4();   // own 4 newest stage-loads may stay in flight; older all landed
    } else if (t + 1 < nt) {
      VM0();   // tail: next tile's stages (issued at t-1) must fully land
    }
    SBAR();
  }

  // ---- epilogue: C/D layout col=lane&15, row=(lane>>4)*4+reg ----
#pragma unroll
  for (int ni = 0; ni < 4; ++ni) {
    const int col = bn0 + wn * 64 + ni * 16 + lr;
    const float bv = bias[col];
#pragma unroll
    for (int mi = 0; mi < 8; ++mi) {
      const int row0 = bm0 + wm * 128 + mi * 16 + g * 4;
#pragma unroll
      for (int j = 0; j < 4; ++j)
        y[(size_t)(row0 + j) * n + col] = acc[mi][ni][j] + bv;
    }
  }
}

// ---------------- fallback (no ws needed) ----------------

#define LDP 72

__global__ __launch_bounds__(256) void circ_gemm_fb(
    const float* __restrict__ x, const float* __restrict__ r,
    const float* __restrict__ bias, float* __restrict__ y, int n) {
  __shared__ unsigned short Asf[128][LDP];
  __shared__ unsigned short Bsf[128][LDP];

  const int tid = threadIdx.x;
  const int wid = tid >> 6;
  const int lane = tid & 63;
  const int bm0 = blockIdx.y * 128;
  const int bn0 = blockIdx.x * 128;
  const int m0w = (wid >> 1) * 64;
  const int n0w = (wid & 1) * 64;
  const int lr = lane & 15;
  const int lk = (lane >> 4) * 8;
  const int mask = n - 1;

  f32x4 acc[4][4];
#pragma unroll
  for (int i = 0; i < 4; ++i)
#pragma unroll
    for (int j = 0; j < 4; ++j) acc[i][j] = (f32x4){0.f, 0.f, 0.f, 0.f};

  const int arow = tid >> 4;
  const int acol = (tid & 15) * 4;
  const int bnn = tid >> 1;
  const int bk0 = (tid & 1) * 32;

  for (int k0 = 0; k0 < n; k0 += 64) {
#pragma unroll
    for (int p = 0; p < 8; ++p) {
      const float4 v =
          *(const float4*)&x[(size_t)(bm0 + arow + p * 16) * n + k0 + acol];
      us4 hh;
      hh.x = f2bf(v.x); hh.y = f2bf(v.y); hh.z = f2bf(v.z); hh.w = f2bf(v.w);
      *(us4*)&Asf[arow + p * 16][acol] = hh;
    }
    {
      const int base = k0 + bk0 - bn0 - bnn;
#pragma unroll
      for (int kq = 0; kq < 32; kq += 4) {
        us4 hh;
        hh.x = f2bf(r[(base + kq + 0) & mask]);
        hh.y = f2bf(r[(base + kq + 1) & mask]);
        hh.z = f2bf(r[(base + kq + 2) & mask]);
        hh.w = f2bf(r[(base + kq + 3) & mask]);
        *(us4*)&Bsf[bnn][bk0 + kq] = hh;
      }
    }
    __syncthreads();

#pragma unroll
    for (int kk = 0; kk < 2; ++kk) {
      bf16x8 af[4], bfr[4];
#pragma unroll
      for (int mi = 0; mi < 4; ++mi)
        af[mi] = *(const bf16x8*)&Asf[m0w + mi * 16 + lr][kk * 32 + lk];
#pragma unroll
      for (int ni = 0; ni < 4; ++ni)
        bfr[ni] = *(const bf16x8*)&Bsf[n0w + ni * 16 + lr][kk * 32 + lk];
#pragma unroll
      for (int mi = 0; mi < 4; ++mi)
#pragma unroll
        for (int ni = 0; ni < 4; ++ni)
          acc[mi][ni] = __builtin_amdgcn_mfma_f32_16x16x32_bf16(
              af[mi], bfr[ni], acc[mi][ni], 0, 0, 0);
    }
    __syncthreads();
  }

#pragma unroll
  for (int ni = 0; ni < 4; ++ni) {
    const int col = bn0 + n0w + ni * 16 + lr;
    const float bv = bias[col];
#pragma unroll
    for (int mi = 0; mi < 4; ++mi) {
      const int row0 = bm0 + m0w + mi * 16 + (lane >> 4) * 4;
#pragma unroll
      for (int j = 0; j < 4; ++j)
        y[(size_t)(row0 + j) * n + col] = acc[mi][ni][j] + bv;
    }
  }
}

// ---------------- launch ----------------

extern "C" void kernel_launch(void* const* d_in, const int* in_sizes, int n_in,
                              void* d_out, int out_size, void* d_ws,
                              size_t ws_size, hipStream_t stream) {
  const float* x = (const float*)d_in[0];
  const float* r = (const float*)d_in[1];
  const float* b = (const float*)d_in[2];
  float* y = (float*)d_out;
  const int n = in_sizes[1];          // 4096
  const int batch = in_sizes[0] / n;  // 8192

  const size_t xb_elems = (size_t)batch * n;
  const size_t bt_elems = (size_t)n * n;
  const size_t need = (xb_elems + bt_elems) * sizeof(unsigned short);

  if (ws_size >= need && (n % 256) == 0 && (batch % 256) == 0) {
    unsigned short* xb = (unsigned short*)d_ws;
    unsigned short* bt = xb + xb_elems;
    int logn = 31 - __builtin_clz((unsigned)n);
    conv_x_kernel<<<2048, 256, 0, stream>>>(x, xb, xb_elems / 8);
    build_bt_kernel<<<1024, 256, 0, stream>>>(r, bt, n, logn);
    dim3 grid((batch / 256) * (n / 256));
    circ_gemm5<<<grid, 512, 0, stream>>>(xb, bt, b, y, n, n / 256);
  } else {
    dim3 grid(n / 128, batch / 128);
    circ_gemm_fb<<<grid, 256, 0, stream>>>(x, r, b, y, n);
  }
}